// Round 12
// baseline (5344.948 us; speedup 1.0000x reference)
//
#include <hip/hip_runtime.h>
#include <hip/hip_bf16.h>
#include <math.h>

constexpr int kT = 64, kB = 256, kS = 1024, kA = 32, kH = 2048;
constexpr int kH3 = 3 * kH;   // 6144
constexpr int kS2 = 2 * kS;   // 2048

typedef __hip_bfloat16 bf16;
typedef __bf16 bf16x8 __attribute__((ext_vector_type(8)));
typedef float f32x4 __attribute__((ext_vector_type(4)));

__device__ inline f32x4 mfma16(bf16x8 a, bf16x8 b, f32x4 c) {
  return __builtin_amdgcn_mfma_f32_16x16x32_bf16(a, b, c, 0, 0, 0);
}

__device__ inline void gload16(const void* g, void* l) {
  __builtin_amdgcn_global_load_lds(
      (const __attribute__((address_space(1))) void*)g,
      (__attribute__((address_space(3))) void*)l, 16, 0, 0);
}

// counted-vmcnt pipeline sync (per-wave count uniform across waves).
#define PSYNC(vm)                                              \
  do {                                                         \
    asm volatile("s_waitcnt vmcnt(" #vm ")" ::: "memory");     \
    __builtin_amdgcn_sched_barrier(0);                         \
    __builtin_amdgcn_s_barrier();                              \
    __builtin_amdgcn_sched_barrier(0);                         \
  } while (0)

// write-through bf16 store: lands in L3 (no dirty private-L2 line).
__device__ __forceinline__ void store_wt(const bf16* p, float v) {
  __hip_bfloat16 hb = __float2bfloat16(v);
  unsigned ub = *reinterpret_cast<unsigned short*>(&hb);
  asm volatile("global_store_short %0, %1, off sc0 sc1"
               :: "v"(p), "v"(ub) : "memory");
}

// fence-free flag ops (relaxed RMW executes at the L3 coherence point).
__device__ __forceinline__ void poll_flag(unsigned* f, unsigned tgt) {
  if (threadIdx.x == 0) {
    while (__hip_atomic_fetch_add(f, 0u, __ATOMIC_RELAXED,
                                  __HIP_MEMORY_SCOPE_AGENT) < tgt)
      __builtin_amdgcn_s_sleep(2);
  }
  __syncthreads();
}
__device__ __forceinline__ void post_flag(unsigned* f) {
  // pre: all write-through stores drained (vmcnt0) + __syncthreads() done
  if (threadIdx.x == 0) {
    __hip_atomic_fetch_add(f, 1u, __ATOMIC_RELAXED, __HIP_MEMORY_SCOPE_AGENT);
    asm volatile("s_waitcnt vmcnt(0)" ::: "memory");  // keep per-wave vmcnt uniform
  }
}
// flag idx: 0..3 hidF[m] | 4..7 stF[m] | 12..15 gruF[m]
#define FLG(u, idx) (flags + ((size_t)(u) * 16 + (idx)) * 32)

// ---- BK=32 tiles: [ROWS][32] bf16, row = 4 x 16B chunks.
// Swizzle chunk ^= (row>>1)&3; source pre-swizzled, read applies same XOR.

template<int ROWS>
__device__ __forceinline__ void stage32(const bf16* __restrict__ g, int ldK, bf16* lds) {
  const int tid = threadIdx.x;
#pragma unroll
  for (int i = 0; i < ROWS / 64; ++i) {
    const int idx = i * 256 + tid;
    const int r = idx >> 2;
    const int cc = (idx & 3) ^ ((r >> 1) & 3);
    gload16(g + (size_t)r * ldK + cc * 8, lds + (size_t)(i * 4 + (tid >> 6)) * 512);
  }
}

// Two 32-row tiles staged uniformly (1 load per thread, uniform vmcnt).
__device__ __forceinline__ void stage32_pair(const bf16* __restrict__ gM,
                                             const bf16* __restrict__ gS, int ldK,
                                             bf16* ldsM, bf16* ldsS) {
  const int tid = threadIdx.x;
  const int half = tid >> 7;
  const int t2 = tid & 127;
  const int r = t2 >> 2;
  const int cc = (t2 & 3) ^ ((r >> 1) & 3);
  const bf16* src = half ? gS : gM;
  bf16* dst = (half ? ldsS : ldsM) + ((tid >> 6) & 1) * 512;
  gload16(src + (size_t)r * ldK + cc * 8, dst);
}

__device__ __forceinline__ bf16x8 ldfrag32(const bf16* lds, int row0) {
  const int lane = threadIdx.x & 63;
  const int row = row0 + (lane & 15);
  const int c = (lane >> 4) ^ ((row >> 1) & 3);
  return *reinterpret_cast<const bf16x8*>(lds + row * 32 + c * 8);
}

// ---------- prep kernels ----------

__global__ void k_zero(unsigned* p, int n) {
  int i = blockIdx.x * 256 + threadIdx.x;
  if (i < n) p[i] = 0u;
}

__global__ void k_cvt(const float* __restrict__ src, bf16* __restrict__ dst, int n) {
  int i = (blockIdx.x * 256 + threadIdx.x) * 4;
  if (i >= n) return;
  float4 v = *reinterpret_cast<const float4*>(src + i);
  dst[i + 0] = __float2bfloat16(v.x);
  dst[i + 1] = __float2bfloat16(v.y);
  dst[i + 2] = __float2bfloat16(v.z);
  dst[i + 3] = __float2bfloat16(v.w);
}

__global__ void k_cvt_belief(const float* __restrict__ src, bf16* __restrict__ dstb,
                             float* __restrict__ dstf, int n) {
  int i = (blockIdx.x * 256 + threadIdx.x) * 4;
  if (i >= n) return;
  float4 v = *reinterpret_cast<const float4*>(src + i);
  dstb[i + 0] = __float2bfloat16(v.x);
  dstb[i + 1] = __float2bfloat16(v.y);
  dstb[i + 2] = __float2bfloat16(v.z);
  dstb[i + 3] = __float2bfloat16(v.w);
  *reinterpret_cast<float4*>(dstf + i) = v;
}

__global__ __launch_bounds__(256) void k_transpose(const float* __restrict__ src,
                                                   bf16* __restrict__ dst, int R, int C) {
  __shared__ float tile[32][33];
  const int c0 = blockIdx.x * 32, r0 = blockIdx.y * 32;
  const int tx = threadIdx.x & 31, ty = threadIdx.x >> 5;
#pragma unroll
  for (int i = 0; i < 32; i += 8)
    tile[ty + i][tx] = src[(size_t)(r0 + ty + i) * C + c0 + tx];
  __syncthreads();
#pragma unroll
  for (int i = 0; i < 32; i += 8)
    dst[(size_t)(c0 + ty + i) * R + r0 + tx] = __float2bfloat16(tile[tx][ty + i]);
}

__global__ __launch_bounds__(256) void k_actb(const float* __restrict__ actions,
                                              const float* __restrict__ Wtpa,
                                              const float* __restrict__ b_tp,
                                              bf16* __restrict__ actb) {
  __shared__ float a_s[64][32];
  const int tb0 = blockIdx.x * 64;
  const int tid = threadIdx.x;
  for (int i = tid; i < 64 * 32 / 4; i += 256) {
    float4 v = *reinterpret_cast<const float4*>(actions + (size_t)tb0 * 32 + i * 4);
    reinterpret_cast<float4*>(&a_s[0][0])[i] = v;
  }
  __syncthreads();
#pragma unroll
  for (int j = 0; j < 8; ++j) {
    const int c = j * 256 + tid;
    float w[32];
#pragma unroll
    for (int a = 0; a < 32; ++a) w[a] = Wtpa[a * kH + c];
    const float bt = b_tp[c];
    for (int r = 0; r < 64; ++r) {
      float acc = bt;
#pragma unroll
      for (int a = 0; a < 32; ++a) acc += a_s[r][a] * w[a];
      actb[(size_t)(tb0 + r) * kH + c] = __float2bfloat16(acc);
    }
  }
}

// ---------- phase A: persistent state chain (hidden + post only) ----------
// 256 blocks; per-XCD weight set = WtpT 0.5 MB + WpostT 1 MB = 1.5 MB -> L2
// resident across all 64 steps. stR/hidR are linear per-step buffers (no
// address reuse within the launch -> no stale-L2 hazard); producers write
// write-through; flags relaxed-RMW (round-9 proven protocol).

__global__ __launch_bounds__(256, 2) void k_phA(
    const bf16* __restrict__ WtpT, const bf16* __restrict__ WpostT,
    const float* __restrict__ b_post, const bf16* __restrict__ actb,
    const float* __restrict__ eps,
    bf16* __restrict__ stR, bf16* __restrict__ hidR,
    float* __restrict__ out_means, float* __restrict__ out_stds,
    float* __restrict__ out_states, unsigned* __restrict__ flags) {
  __shared__ __align__(16) bf16 smem[32768];   // 64 KB
  const int bx = blockIdx.x;
  const int xcd = bx & 7, j = bx >> 3;
  const int tid = threadIdx.x, wv = tid >> 6, lane = tid & 63;
  const int l16 = lane & 15, k8 = lane >> 4;
  const int wr = (wv >> 1) * 32, wc = (wv & 1) * 32;

  if (j < 16) {
    // ======== hidden(u) = relu(stR[u] @ WtpT^T + actb[u]) -> hidR[u] (wt)
    const int m = j >> 2, m0 = m * 64;
    const int n0 = xcd * 256 + (j & 3) * 64;
    const bf16* Bg = WtpT + (size_t)n0 * kS;
    for (int u = 0; u < kT; ++u) {
      if (u > 0) poll_flag(FLG(u, 4 + m), 32);   // stR[u] from post(u-1)
      const bf16* Ag = stR + (size_t)u * kB * kS + (size_t)m0 * kS;
      f32x4 acc[2][2] = {};
#define STG_H(t, s)                                            \
  {                                                            \
    stage32<64>(Ag + (t) * 32, kS, smem + (s) * 4096);         \
    stage32<64>(Bg + (t) * 32, kS, smem + (s) * 4096 + 2048);  \
  }
      STG_H(0, 0); STG_H(1, 1); STG_H(2, 2); STG_H(3, 3); STG_H(4, 4);
      int cs = 0;
      for (int kt = 0; kt < 32; ++kt) {
        if (kt < 28) PSYNC(8);
        else if (kt == 28) PSYNC(6);
        else if (kt == 29) PSYNC(4);
        else if (kt == 30) PSYNC(2);
        else PSYNC(0);
        if (kt + 5 < 32) STG_H(kt + 5, cs == 0 ? 5 : cs - 1);
        const bf16* As = smem + cs * 4096;
        const bf16* Bs = As + 2048;
        bf16x8 a0 = ldfrag32(As, wr), a1 = ldfrag32(As, wr + 16);
        bf16x8 b0 = ldfrag32(Bs, wc), b1 = ldfrag32(Bs, wc + 16);
        acc[0][0] = mfma16(a0, b0, acc[0][0]);
        acc[0][1] = mfma16(a0, b1, acc[0][1]);
        acc[1][0] = mfma16(a1, b0, acc[1][0]);
        acc[1][1] = mfma16(a1, b1, acc[1][1]);
        cs = (cs == 5) ? 0 : cs + 1;
      }
#undef STG_H
      const bf16* at = actb + (size_t)u * kB * kH;
      bf16* hw = hidR + (size_t)u * kB * kH;
#pragma unroll
      for (int mi = 0; mi < 2; ++mi)
#pragma unroll
        for (int ni = 0; ni < 2; ++ni)
#pragma unroll
          for (int ii = 0; ii < 4; ++ii) {
            int row = m0 + wr + mi * 16 + k8 * 4 + ii;
            int col = n0 + wc + ni * 16 + l16;
            float h = acc[mi][ni][ii] + __bfloat162float(at[(size_t)row * kH + col]);
            store_wt(hw + (size_t)row * kH + col, fmaxf(h, 0.f));
          }
      asm volatile("s_waitcnt vmcnt(0)" ::: "memory");
      __syncthreads();
      post_flag(FLG(u, 0 + m));
    }
  } else {
    // ======== post(u): mean/std/state from hidR[u]; writes stR[u+1] (wt)
    const int jj = j - 16;
    const int m = jj >> 2, m0 = m * 64;
    const int p0 = xcd * 128 + (jj & 3) * 32;
    const int wpc = (wv & 1) * 16;
    const bf16* Mg = WpostT + (size_t)p0 * kH;
    const bf16* Sg = WpostT + (size_t)(kS + p0) * kH;
    for (int u = 0; u < kT; ++u) {
      poll_flag(FLG(u, 0 + m), 32);                  // hidR[u] ready
      const bf16* Ag = hidR + (size_t)u * kB * kH + (size_t)m0 * kH;
      f32x4 accM[2] = {}, accS[2] = {};
#define STG_P(t, s)                                                        \
  {                                                                        \
    stage32<64>(Ag + (t) * 32, kH, smem + (s) * 4096);                     \
    stage32_pair(Mg + (t) * 32, Sg + (t) * 32, kH,                         \
                 smem + (s) * 4096 + 2048, smem + (s) * 4096 + 3072);      \
  }
      STG_P(0, 0); STG_P(1, 1); STG_P(2, 2); STG_P(3, 3); STG_P(4, 4);
      int cs = 0;
      for (int kt = 0; kt < 64; ++kt) {
        if (kt < 60) PSYNC(8);
        else if (kt == 60) PSYNC(6);
        else if (kt == 61) PSYNC(4);
        else if (kt == 62) PSYNC(2);
        else PSYNC(0);
        if (kt + 5 < 64) STG_P(kt + 5, cs == 0 ? 5 : cs - 1);
        const bf16* As = smem + cs * 4096;
        bf16x8 a0 = ldfrag32(As, wr), a1 = ldfrag32(As, wr + 16);
        bf16x8 bm = ldfrag32(As + 2048, wpc);
        bf16x8 bs = ldfrag32(As + 3072, wpc);
        accM[0] = mfma16(a0, bm, accM[0]);
        accM[1] = mfma16(a1, bm, accM[1]);
        accS[0] = mfma16(a0, bs, accS[0]);
        accS[1] = mfma16(a1, bs, accS[1]);
        cs = (cs == 5) ? 0 : cs + 1;
      }
#undef STG_P
      const float* et = eps + (size_t)u * kB * kS;
      float* mt = out_means + (size_t)u * kB * kS;
      float* sdt = out_stds + (size_t)u * kB * kS;
      float* xt = out_states + (size_t)u * kB * kS;
      bf16* sw = stR + (size_t)(u + 1) * kB * kS;
#pragma unroll
      for (int mi = 0; mi < 2; ++mi)
#pragma unroll
        for (int ii = 0; ii < 4; ++ii) {
          int row = m0 + wr + mi * 16 + k8 * 4 + ii;
          int p = p0 + wpc + l16;
          float mean = accM[mi][ii] + b_post[p];
          float sraw = accS[mi][ii] + b_post[kS + p];
          float sp = (sraw > 20.f) ? sraw : log1pf(expf(sraw));
          float sv = mean + sp * et[(size_t)row * kS + p];
          mt[(size_t)row * kS + p] = mean;
          sdt[(size_t)row * kS + p] = sp;
          xt[(size_t)row * kS + p] = sv;
          store_wt(sw + (size_t)row * kS + p, sv);
        }
      asm volatile("s_waitcnt vmcnt(0)" ::: "memory");
      __syncthreads();
      post_flag(FLG(u + 1, 4 + m));
    }
  }
}

// ---------- phase B: batched GI = hidden_chunk @ Wih^T + b_ih ----------
// Grid (48, 2*CH). Wih read ONCE per chunk (streamed through L2 with reuse
// across m-blocks, XCD-affine n0). Normal stores (consumed next dispatch).

__global__ __launch_bounds__(256) void k_gi(const bf16* __restrict__ hidC,
                                            const bf16* __restrict__ Wih,
                                            const float* __restrict__ b_ih,
                                            bf16* __restrict__ GIc) {
  __shared__ __align__(16) bf16 smem[32768];
  const int bx = blockIdx.x;
  const int n0 = (bx & 7) * 768 + (bx >> 3) * 128;  // XCD-affine, 48 n-blocks
  const int m0 = blockIdx.y * 128;
  const int tid = threadIdx.x, wv = tid >> 6, lane = tid & 63;
  const int l16 = lane & 15, k8 = lane >> 4;
  const int wrg = (wv >> 1) * 64, wcg = (wv & 1) * 64;
  const bf16* Ag = hidC + (size_t)m0 * kH;
  const bf16* Bg = Wih + (size_t)n0 * kH;
  f32x4 acc[4][4] = {};
#define STG_I(t, s)                                             \
  {                                                             \
    stage32<128>(Ag + (t) * 32, kH, smem + (s) * 8192);         \
    stage32<128>(Bg + (t) * 32, kH, smem + (s) * 8192 + 4096);  \
  }
  STG_I(0, 0); STG_I(1, 1); STG_I(2, 2);
  for (int kt = 0; kt < 64; ++kt) {
    if (kt < 62) PSYNC(8);
    else if (kt == 62) PSYNC(4);
    else PSYNC(0);
    if (kt + 3 < 64) STG_I(kt + 3, (kt + 3) & 3);
    const bf16* As = smem + (kt & 3) * 8192;
    const bf16* Bs = As + 4096;
    bf16x8 a[4], b[4];
#pragma unroll
    for (int i = 0; i < 4; ++i) a[i] = ldfrag32(As, wrg + i * 16);
#pragma unroll
    for (int i = 0; i < 4; ++i) b[i] = ldfrag32(Bs, wcg + i * 16);
#pragma unroll
    for (int mi = 0; mi < 4; ++mi)
#pragma unroll
      for (int ni = 0; ni < 4; ++ni)
        acc[mi][ni] = mfma16(a[mi], b[ni], acc[mi][ni]);
  }
#undef STG_I
#pragma unroll
  for (int mi = 0; mi < 4; ++mi)
#pragma unroll
    for (int ni = 0; ni < 4; ++ni)
#pragma unroll
      for (int ii = 0; ii < 4; ++ii) {
        int row = m0 + wrg + mi * 16 + k8 * 4 + ii;
        int col = n0 + wcg + ni * 16 + l16;
        GIc[(size_t)row * kH3 + col] = __float2bfloat16(acc[mi][ni][ii] + b_ih[col]);
      }
}

// ---------- phase C: persistent belief chain (gru only) ----------
// 128 blocks; per-XCD weight set = Whh 3 MB -> L2-resident across steps.
// GIc precomputed (phase B, prior dispatch -> no poll). bbR linear per-step.

__global__ __launch_bounds__(256, 2) void k_phC(
    int c0, int nsteps,
    const bf16* __restrict__ Whh, const float* __restrict__ b_hh,
    const bf16* __restrict__ GIc, bf16* __restrict__ bbR,
    float* __restrict__ belief_f32, float* __restrict__ out_beliefs,
    unsigned* __restrict__ flags) {
  __shared__ __align__(16) bf16 smem[32768];
  const int bx = blockIdx.x;
  const int xcd = bx & 7, jj = bx >> 3;
  const int tid = threadIdx.x, wv = tid >> 6, lane = tid & 63;
  const int l16 = lane & 15, k8 = lane >> 4;
  const int wr = (wv >> 1) * 32, wc = (wv & 1) * 32;
  const int m = jj >> 2, m0 = m * 64;
  const int n0 = xcd * 256 + (jj & 3) * 64;
  const bf16* G0 = Whh + (size_t)(0 * kH + n0) * kH;
  const bf16* G1 = Whh + (size_t)(1 * kH + n0) * kH;
  const bf16* G2 = Whh + (size_t)(2 * kH + n0) * kH;
  for (int u = c0; u < c0 + nsteps; ++u) {
    if (u > 0) poll_flag(FLG(u - 1, 12 + m), 32);   // bbR[u] from gru(u-1)
    const bf16* Ag = bbR + (size_t)u * kB * kH + (size_t)m0 * kH;
    f32x4 acc[3][2][2] = {};
#define STG_G(t, s)                                            \
  {                                                            \
    stage32<64>(Ag + (t) * 32, kH, smem + (s) * 8192);         \
    stage32<64>(G0 + (t) * 32, kH, smem + (s) * 8192 + 2048);  \
    stage32<64>(G1 + (t) * 32, kH, smem + (s) * 8192 + 4096);  \
    stage32<64>(G2 + (t) * 32, kH, smem + (s) * 8192 + 6144);  \
  }
    STG_G(0, 0); STG_G(1, 1); STG_G(2, 2);
    for (int kt = 0; kt < 64; ++kt) {
      if (kt < 62) PSYNC(8);
      else if (kt == 62) PSYNC(4);
      else PSYNC(0);
      if (kt + 3 < 64) STG_G(kt + 3, (kt + 3) & 3);
      const bf16* As = smem + (kt & 3) * 8192;
      bf16x8 a0 = ldfrag32(As, wr), a1 = ldfrag32(As, wr + 16);
#pragma unroll
      for (int g = 0; g < 3; ++g) {
        const bf16* Bs = As + 2048 * (1 + g);
        bf16x8 b0 = ldfrag32(Bs, wc), b1 = ldfrag32(Bs, wc + 16);
        acc[g][0][0] = mfma16(a0, b0, acc[g][0][0]);
        acc[g][0][1] = mfma16(a0, b1, acc[g][0][1]);
        acc[g][1][0] = mfma16(a1, b0, acc[g][1][0]);
        acc[g][1][1] = mfma16(a1, b1, acc[g][1][1]);
      }
    }
#undef STG_G
    const bf16* gi = GIc + (size_t)(u - c0) * kB * kH3;
    float* outB = out_beliefs + (size_t)u * kB * kH;
    bf16* bw = bbR + (size_t)(u + 1) * kB * kH;
#pragma unroll
    for (int mi = 0; mi < 2; ++mi)
#pragma unroll
      for (int ni = 0; ni < 2; ++ni)
#pragma unroll
        for (int ii = 0; ii < 4; ++ii) {
          int row = m0 + wr + mi * 16 + k8 * 4 + ii;
          int col = n0 + wc + ni * 16 + l16;
          const bf16* gr = gi + (size_t)row * kH3;
          float hr = acc[0][mi][ni][ii] + b_hh[col];
          float hz = acc[1][mi][ni][ii] + b_hh[kH + col];
          float hn = acc[2][mi][ni][ii] + b_hh[2 * kH + col];
          float r = 1.f / (1.f + expf(-(__bfloat162float(gr[col]) + hr)));
          float z = 1.f / (1.f + expf(-(__bfloat162float(gr[kH + col]) + hz)));
          float n = tanhf(__bfloat162float(gr[2 * kH + col]) + r * hn);
          float bel = belief_f32[(size_t)row * kH + col];   // block-private
          float nb = (1.f - z) * n + z * bel;
          outB[(size_t)row * kH + col] = nb;
          belief_f32[(size_t)row * kH + col] = nb;
          store_wt(bw + (size_t)row * kH + col, nb);
        }
    asm volatile("s_waitcnt vmcnt(0)" ::: "memory");
    __syncthreads();
    post_flag(FLG(u, 12 + m));
  }
}

// ---------- host ----------

extern "C" void kernel_launch(void* const* d_in, const int* in_sizes, int n_in,
                              void* d_out, int out_size, void* d_ws, size_t ws_size,
                              hipStream_t stream) {
  const float* prev_state  = (const float*)d_in[0];
  const float* actions     = (const float*)d_in[1];
  const float* prev_belief = (const float*)d_in[2];
  const float* eps         = (const float*)d_in[3];
  const float* W_ih        = (const float*)d_in[4];
  const float* W_hh        = (const float*)d_in[5];
  const float* b_ih        = (const float*)d_in[6];
  const float* b_hh        = (const float*)d_in[7];
  const float* W_tp        = (const float*)d_in[8];
  const float* b_tp        = (const float*)d_in[9];
  const float* W_post      = (const float*)d_in[10];
  const float* b_post      = (const float*)d_in[11];

  float* out_beliefs = (float*)d_out;                          // [T,B,H]
  float* out_states  = out_beliefs + (size_t)kT * kB * kH;     // [T,B,S]
  float* out_means   = out_states + (size_t)kT * kB * kS;
  float* out_stds    = out_means + (size_t)kT * kB * kS;

  size_t off = 0;
  auto alloc = [&](size_t bytes) {
    void* r = (char*)d_ws + off;
    off += (bytes + 255) & ~(size_t)255;
    return r;
  };
  const int nFlagWords = (kT + 1) * 16 * 32;
  unsigned* flags = (unsigned*)alloc((size_t)nFlagWords * sizeof(unsigned));
  bf16* Wih_b  = (bf16*)alloc((size_t)kH3 * kH * 2);
  bf16* Whh_b  = (bf16*)alloc((size_t)kH3 * kH * 2);
  bf16* WtpT   = (bf16*)alloc((size_t)kH * kS * 2);     // [H][S]
  bf16* WpostT = (bf16*)alloc((size_t)kS2 * kH * 2);    // [2S][H]
  bf16* actb   = (bf16*)alloc((size_t)kT * kB * kH * 2);
  float* belief_f32 = (float*)alloc((size_t)kB * kH * 4);
  bf16* stR  = (bf16*)alloc((size_t)(kT + 1) * kB * kS * 2);   // linear per-step
  bf16* hidR = (bf16*)alloc((size_t)kT * kB * kH * 2);         // linear per-step
  bf16* bbR  = (bf16*)alloc((size_t)(kT + 1) * kB * kH * 2);   // linear per-step
  int CH = 64;
  while (CH > 1 && off + (size_t)CH * kB * kH3 * 2 + 4096 > ws_size) CH >>= 1;
  bf16* GIc = (bf16*)alloc((size_t)CH * kB * kH3 * 2);

  // prep
  k_zero<<<dim3((nFlagWords + 255) / 256), 256, 0, stream>>>(flags, nFlagWords);
  k_cvt<<<dim3(kH3 * kH / 1024), 256, 0, stream>>>(W_ih, Wih_b, kH3 * kH);
  k_cvt<<<dim3(kH3 * kH / 1024), 256, 0, stream>>>(W_hh, Whh_b, kH3 * kH);
  k_cvt<<<dim3(kB * kS / 1024), 256, 0, stream>>>(prev_state, stR, kB * kS);
  k_cvt_belief<<<dim3(kB * kH / 1024), 256, 0, stream>>>(prev_belief, bbR, belief_f32, kB * kH);
  k_transpose<<<dim3(kH / 32, kS / 32), 256, 0, stream>>>(W_tp, WtpT, kS, kH);
  k_transpose<<<dim3(kS2 / 32, kH / 32), 256, 0, stream>>>(W_post, WpostT, kH, kS2);
  k_actb<<<dim3(kT * kB / 64), 256, 0, stream>>>(actions, W_tp + (size_t)kS * kH, b_tp, actb);

  // phase A: full state chain, one persistent launch (weights L2-resident)
  k_phA<<<dim3(256), dim3(256), 0, stream>>>(
      WtpT, WpostT, b_post, actb, eps, stR, hidR,
      out_means, out_stds, out_states, flags);

  // phases B + C per chunk: batched GI GEMM, then persistent gru chain
  for (int c0 = 0; c0 < kT; c0 += CH) {
    k_gi<<<dim3(48, 2 * CH), 256, 0, stream>>>(
        hidR + (size_t)c0 * kB * kH, Wih_b, b_ih, GIc);
    k_phC<<<dim3(128), dim3(256), 0, stream>>>(
        c0, CH, Whh_b, b_hh, GIc, bbR, belief_f32, out_beliefs, flags);
  }
}

// Round 13
// 2532.831 us; speedup vs baseline: 2.1103x; 2.1103x over previous
//
#include <hip/hip_runtime.h>
#include <hip/hip_bf16.h>
#include <math.h>

constexpr int kT = 64, kB = 256, kS = 1024, kA = 32, kH = 2048;
constexpr int kH3 = 3 * kH;   // 6144
constexpr int kS2 = 2 * kS;   // 2048

typedef __hip_bfloat16 bf16;
typedef __bf16 bf16x8 __attribute__((ext_vector_type(8)));
typedef float f32x4 __attribute__((ext_vector_type(4)));

__device__ inline f32x4 mfma16(bf16x8 a, bf16x8 b, f32x4 c) {
  return __builtin_amdgcn_mfma_f32_16x16x32_bf16(a, b, c, 0, 0, 0);
}

__device__ inline void gload16(const void* g, void* l) {
  __builtin_amdgcn_global_load_lds(
      (const __attribute__((address_space(1))) void*)g,
      (__attribute__((address_space(3))) void*)l, 16, 0, 0);
}

// counted-vmcnt pipeline sync (per-wave count uniform across waves!).
#define PSYNC(vm)                                              \
  do {                                                         \
    asm volatile("s_waitcnt vmcnt(" #vm ")" ::: "memory");     \
    __builtin_amdgcn_sched_barrier(0);                         \
    __builtin_amdgcn_s_barrier();                              \
    __builtin_amdgcn_sched_barrier(0);                         \
  } while (0)

// ---- BK=32 tiles: [ROWS][32] bf16, row = 4 x 16B chunks.
// Swizzle chunk ^= (row>>1)&3; source pre-swizzled, read applies same XOR.

template<int ROWS>
__device__ __forceinline__ void stage32(const bf16* __restrict__ g, int ldK, bf16* lds) {
  const int tid = threadIdx.x;
#pragma unroll
  for (int i = 0; i < ROWS / 64; ++i) {
    const int idx = i * 256 + tid;
    const int r = idx >> 2;
    const int cc = (idx & 3) ^ ((r >> 1) & 3);
    gload16(g + (size_t)r * ldK + cc * 8, lds + (size_t)(i * 4 + (tid >> 6)) * 512);
  }
}

// Two 32-row tiles staged uniformly: waves 0-1 -> tile M, waves 2-3 -> tile S.
// Every thread issues exactly 1 load (uniform per-wave vmcnt bookkeeping).
__device__ __forceinline__ void stage32_pair(const bf16* __restrict__ gM,
                                             const bf16* __restrict__ gS, int ldK,
                                             bf16* ldsM, bf16* ldsS) {
  const int tid = threadIdx.x;
  const int half = tid >> 7;           // 0: M, 1: S
  const int t2 = tid & 127;
  const int r = t2 >> 2;
  const int cc = (t2 & 3) ^ ((r >> 1) & 3);
  const bf16* src = half ? gS : gM;
  bf16* dst = (half ? ldsS : ldsM) + ((tid >> 6) & 1) * 512;
  gload16(src + (size_t)r * ldK + cc * 8, dst);
}

// fragment: lane l -> row row0+(l&15), k = (l>>4)*8..+7
__device__ __forceinline__ bf16x8 ldfrag32(const bf16* lds, int row0) {
  const int lane = threadIdx.x & 63;
  const int row = row0 + (lane & 15);
  const int c = (lane >> 4) ^ ((row >> 1) & 3);
  return *reinterpret_cast<const bf16x8*>(lds + row * 32 + c * 8);
}

// ---------- prep kernels ----------

__global__ void k_zero(unsigned* p, int n) {
  int i = blockIdx.x * 64 + threadIdx.x;
  if (i < n) p[i] = 0u;
}

__global__ void k_cvt(const float* __restrict__ src, bf16* __restrict__ dst, int n) {
  int i = (blockIdx.x * 256 + threadIdx.x) * 4;
  if (i >= n) return;
  float4 v = *reinterpret_cast<const float4*>(src + i);
  dst[i + 0] = __float2bfloat16(v.x);
  dst[i + 1] = __float2bfloat16(v.y);
  dst[i + 2] = __float2bfloat16(v.z);
  dst[i + 3] = __float2bfloat16(v.w);
}

__global__ void k_cvt_belief(const float* __restrict__ src, bf16* __restrict__ dstb,
                             float* __restrict__ dstf, int n) {
  int i = (blockIdx.x * 256 + threadIdx.x) * 4;
  if (i >= n) return;
  float4 v = *reinterpret_cast<const float4*>(src + i);
  dstb[i + 0] = __float2bfloat16(v.x);
  dstb[i + 1] = __float2bfloat16(v.y);
  dstb[i + 2] = __float2bfloat16(v.z);
  dstb[i + 3] = __float2bfloat16(v.w);
  *reinterpret_cast<float4*>(dstf + i) = v;
}

__global__ __launch_bounds__(256) void k_transpose(const float* __restrict__ src,
                                                   bf16* __restrict__ dst, int R, int C) {
  __shared__ float tile[32][33];
  const int c0 = blockIdx.x * 32, r0 = blockIdx.y * 32;
  const int tx = threadIdx.x & 31, ty = threadIdx.x >> 5;
#pragma unroll
  for (int i = 0; i < 32; i += 8)
    tile[ty + i][tx] = src[(size_t)(r0 + ty + i) * C + c0 + tx];
  __syncthreads();
#pragma unroll
  for (int i = 0; i < 32; i += 8)
    dst[(size_t)(c0 + ty + i) * R + r0 + tx] = __float2bfloat16(tile[tx][ty + i]);
}

__global__ __launch_bounds__(256) void k_actb(const float* __restrict__ actions,
                                              const float* __restrict__ Wtpa,
                                              const float* __restrict__ b_tp,
                                              bf16* __restrict__ actb) {
  __shared__ float a_s[64][32];
  const int tb0 = blockIdx.x * 64;
  const int tid = threadIdx.x;
  for (int i = tid; i < 64 * 32 / 4; i += 256) {
    float4 v = *reinterpret_cast<const float4*>(actions + (size_t)tb0 * 32 + i * 4);
    reinterpret_cast<float4*>(&a_s[0][0])[i] = v;
  }
  __syncthreads();
#pragma unroll
  for (int j = 0; j < 8; ++j) {
    const int c = j * 256 + tid;
    float w[32];
#pragma unroll
    for (int a = 0; a < 32; ++a) w[a] = Wtpa[a * kH + c];
    const float bt = b_tp[c];
    for (int r = 0; r < 64; ++r) {
      float acc = bt;
#pragma unroll
      for (int a = 0; a < 32; ++a) acc += a_s[r][a] * w[a];
      actb[(size_t)(tb0 + r) * kH + c] = __float2bfloat16(acc);
    }
  }
}

// ---------- mega step kernel: one launch per time step ----------
// 480 blocks, 64 KB LDS, 2 blocks/CU => all co-resident (capacity 512).
// Roles by j = bx>>3 (xcd = bx&7):
//   j<16  : hidden(u)   [waits on post flag via RELAXED rmw poll — no fences]
//   j<32  : gru(u-2)
//   j<48  : post(u-1)   [stateb via write-through sc0 sc1 stores; RELAXED release]
//   j<60  : gi(u-1)

__global__ __launch_bounds__(256, 2) void k_mega(
    bf16* __restrict__ stateb, const bf16* __restrict__ WtpT,
    const bf16* __restrict__ actb_t, bf16* __restrict__ hidW,
    int doHidden, int waitPost,
    const bf16* __restrict__ hidR, const bf16* __restrict__ WpostT,
    const float* __restrict__ b_post, const float* __restrict__ eps_t,
    float* __restrict__ means_t, float* __restrict__ stds_t,
    float* __restrict__ states_t, int doPost,
    const bf16* __restrict__ Wih, const float* __restrict__ b_ih,
    bf16* __restrict__ GIw, int doGi,
    const bf16* __restrict__ Whh, const float* __restrict__ b_hh,
    const bf16* __restrict__ GIr, float* __restrict__ belief_f32,
    float* __restrict__ outB, const bf16* __restrict__ bbA,
    bf16* __restrict__ bbB, int doGru,
    unsigned* __restrict__ flags) {
  __shared__ __align__(16) bf16 smem[32768];   // 64 KB
  const int bx = blockIdx.x;
  const int xcd = bx & 7, j = bx >> 3;
  const int tid = threadIdx.x, wv = tid >> 6, lane = tid & 63;
  const int l16 = lane & 15, k8 = lane >> 4;
  const int wr = (wv >> 1) * 32, wc = (wv & 1) * 32;

  if (j < 16) {
    // ======== hidden(u) = relu(state @ WtpT^T + actb); 64x64, NT=32
    if (!doHidden) return;
    const int n0 = xcd * 256 + (j & 3) * 64, m0 = (j >> 2) * 64;
    if (waitPost) {
      if (tid == 0) {
        unsigned* f = flags + (m0 >> 6) * 32;   // flags padded 128B apart
        while (__hip_atomic_fetch_add(f, 0u, __ATOMIC_RELAXED,
                                      __HIP_MEMORY_SCOPE_AGENT) < 32u)
          __builtin_amdgcn_s_sleep(16);
      }
      __syncthreads();
    }
    const bf16* Ag = stateb + (size_t)m0 * kS;
    const bf16* Bg = WtpT + (size_t)n0 * kS;
    f32x4 acc[2][2] = {};
#define STG_H(t, s)                                            \
  {                                                            \
    stage32<64>(Ag + (t) * 32, kS, smem + (s) * 4096);         \
    stage32<64>(Bg + (t) * 32, kS, smem + (s) * 4096 + 2048);  \
  }
    STG_H(0, 0); STG_H(1, 1); STG_H(2, 2);
    for (int kt = 0; kt < 32; ++kt) {
      if (kt < 30) PSYNC(4);
      else if (kt == 30) PSYNC(2);
      else PSYNC(0);
      if (kt + 3 < 32) STG_H(kt + 3, (kt + 3) & 3);
      const bf16* As = smem + (kt & 3) * 4096;
      const bf16* Bs = As + 2048;
      bf16x8 a0 = ldfrag32(As, wr), a1 = ldfrag32(As, wr + 16);
      bf16x8 b0 = ldfrag32(Bs, wc), b1 = ldfrag32(Bs, wc + 16);
      acc[0][0] = mfma16(a0, b0, acc[0][0]);
      acc[0][1] = mfma16(a0, b1, acc[0][1]);
      acc[1][0] = mfma16(a1, b0, acc[1][0]);
      acc[1][1] = mfma16(a1, b1, acc[1][1]);
    }
#undef STG_H
#pragma unroll
    for (int mi = 0; mi < 2; ++mi)
#pragma unroll
      for (int ni = 0; ni < 2; ++ni)
#pragma unroll
        for (int ii = 0; ii < 4; ++ii) {
          int row = m0 + wr + mi * 16 + k8 * 4 + ii;
          int col = n0 + wc + ni * 16 + l16;
          float h = acc[mi][ni][ii] + __bfloat162float(actb_t[(size_t)row * kH + col]);
          hidW[(size_t)row * kH + col] = __float2bfloat16(fmaxf(h, 0.f));
        }
  } else if (j < 32) {
    // ======== gru(u-2): 3-gate gh GEMM + fused elementwise; NT=64
    if (!doGru) return;
    const int jj = j - 16;
    const int n0 = xcd * 256 + (jj & 3) * 64, m0 = (jj >> 2) * 64;
    const bf16* Ag = bbA + (size_t)m0 * kH;
    const bf16* G0 = Whh + (size_t)(0 * kH + n0) * kH;
    const bf16* G1 = Whh + (size_t)(1 * kH + n0) * kH;
    const bf16* G2 = Whh + (size_t)(2 * kH + n0) * kH;
    f32x4 acc[3][2][2] = {};
#define STG_G(t, s)                                            \
  {                                                            \
    stage32<64>(Ag + (t) * 32, kH, smem + (s) * 8192);         \
    stage32<64>(G0 + (t) * 32, kH, smem + (s) * 8192 + 2048);  \
    stage32<64>(G1 + (t) * 32, kH, smem + (s) * 8192 + 4096);  \
    stage32<64>(G2 + (t) * 32, kH, smem + (s) * 8192 + 6144);  \
  }
    STG_G(0, 0); STG_G(1, 1); STG_G(2, 2);
    for (int kt = 0; kt < 64; ++kt) {
      if (kt < 62) PSYNC(8);
      else if (kt == 62) PSYNC(4);
      else PSYNC(0);
      if (kt + 3 < 64) STG_G(kt + 3, (kt + 3) & 3);
      const bf16* As = smem + (kt & 3) * 8192;
      bf16x8 a0 = ldfrag32(As, wr), a1 = ldfrag32(As, wr + 16);
#pragma unroll
      for (int g = 0; g < 3; ++g) {
        const bf16* Bs = As + 2048 * (1 + g);
        bf16x8 b0 = ldfrag32(Bs, wc), b1 = ldfrag32(Bs, wc + 16);
        acc[g][0][0] = mfma16(a0, b0, acc[g][0][0]);
        acc[g][0][1] = mfma16(a0, b1, acc[g][0][1]);
        acc[g][1][0] = mfma16(a1, b0, acc[g][1][0]);
        acc[g][1][1] = mfma16(a1, b1, acc[g][1][1]);
      }
    }
#undef STG_G
#pragma unroll
    for (int mi = 0; mi < 2; ++mi)
#pragma unroll
      for (int ni = 0; ni < 2; ++ni)
#pragma unroll
        for (int ii = 0; ii < 4; ++ii) {
          int row = m0 + wr + mi * 16 + k8 * 4 + ii;
          int col = n0 + wc + ni * 16 + l16;
          const bf16* gi = GIr + (size_t)row * kH3;
          float hr = acc[0][mi][ni][ii] + b_hh[col];
          float hz = acc[1][mi][ni][ii] + b_hh[kH + col];
          float hn = acc[2][mi][ni][ii] + b_hh[2 * kH + col];
          float r = 1.f / (1.f + expf(-(__bfloat162float(gi[col]) + hr)));
          float z = 1.f / (1.f + expf(-(__bfloat162float(gi[kH + col]) + hz)));
          float n = tanhf(__bfloat162float(gi[2 * kH + col]) + r * hn);
          float bel = belief_f32[(size_t)row * kH + col];
          float nb = (1.f - z) * n + z * bel;
          outB[(size_t)row * kH + col] = nb;
          belief_f32[(size_t)row * kH + col] = nb;
          bbB[(size_t)row * kH + col] = __float2bfloat16(nb);
        }
  } else if (j < 48) {
    // ======== post(u-1): mean/std/state; 64 rows x 32 pairs; releases flag
    if (!doPost) return;
    const int jj = j - 32;
    const int p0 = xcd * 128 + (jj & 3) * 32, m0 = (jj >> 2) * 64;
    const int wpc = (wv & 1) * 16;
    const bf16* Ag = hidR + (size_t)m0 * kH;
    const bf16* Mg = WpostT + (size_t)p0 * kH;
    const bf16* Sg = WpostT + (size_t)(kS + p0) * kH;
    f32x4 accM[2] = {}, accS[2] = {};
#define STG_P(t, s)                                                        \
  {                                                                        \
    stage32<64>(Ag + (t) * 32, kH, smem + (s) * 4096);                     \
    stage32_pair(Mg + (t) * 32, Sg + (t) * 32, kH,                         \
                 smem + (s) * 4096 + 2048, smem + (s) * 4096 + 3072);      \
  }
    STG_P(0, 0); STG_P(1, 1); STG_P(2, 2);
    for (int kt = 0; kt < 64; ++kt) {
      if (kt < 62) PSYNC(4);
      else if (kt == 62) PSYNC(2);
      else PSYNC(0);
      if (kt + 3 < 64) STG_P(kt + 3, (kt + 3) & 3);
      const bf16* As = smem + (kt & 3) * 4096;
      bf16x8 a0 = ldfrag32(As, wr), a1 = ldfrag32(As, wr + 16);
      bf16x8 bm = ldfrag32(As + 2048, wpc);
      bf16x8 bs = ldfrag32(As + 3072, wpc);
      accM[0] = mfma16(a0, bm, accM[0]);
      accM[1] = mfma16(a1, bm, accM[1]);
      accS[0] = mfma16(a0, bs, accS[0]);
      accS[1] = mfma16(a1, bs, accS[1]);
    }
#undef STG_P
#pragma unroll
    for (int mi = 0; mi < 2; ++mi)
#pragma unroll
      for (int ii = 0; ii < 4; ++ii) {
        int row = m0 + wr + mi * 16 + k8 * 4 + ii;
        int p = p0 + wpc + l16;
        float mean = accM[mi][ii] + b_post[p];
        float sraw = accS[mi][ii] + b_post[kS + p];
        float sp = (sraw > 20.f) ? sraw : log1pf(expf(sraw));
        float sv = mean + sp * eps_t[(size_t)row * kS + p];
        means_t[(size_t)row * kS + p] = mean;
        stds_t[(size_t)row * kS + p] = sp;
        states_t[(size_t)row * kS + p] = sv;
        // write-through store: lands in L3 directly (no dirty L2 line) so the
        // same-launch hidden role reads fresh data with normal cached loads.
        __hip_bfloat16 hb = __float2bfloat16(sv);
        unsigned ub = *reinterpret_cast<unsigned short*>(&hb);
        const bf16* ap = stateb + (size_t)row * kS + p;
        asm volatile("global_store_short %0, %1, off sc0 sc1"
                     :: "v"(ap), "v"(ub) : "memory");
      }
    asm volatile("s_waitcnt vmcnt(0)" ::: "memory");   // stores reached L3
    __syncthreads();
    if (tid == 0)
      __hip_atomic_fetch_add(flags + (m0 >> 6) * 32, 1u, __ATOMIC_RELAXED,
                             __HIP_MEMORY_SCOPE_AGENT);
  } else {
    // ======== gi(u-1): GI = hidden @ W_ih^T + b_ih; 128x128
    if (!doGi) return;
    const int jj = j - 48;                       // 0..11
    const int n0 = xcd * 768 + (jj % 6) * 128;
    const int m0 = (jj / 6) * 128;
    const int wrg = (wv >> 1) * 64, wcg = (wv & 1) * 64;
    const bf16* Ag = hidR + (size_t)m0 * kH;
    const bf16* Bg = Wih + (size_t)n0 * kH;
    f32x4 acc[4][4] = {};
#define STG_I(t, s)                                             \
  {                                                             \
    stage32<128>(Ag + (t) * 32, kH, smem + (s) * 8192);         \
    stage32<128>(Bg + (t) * 32, kH, smem + (s) * 8192 + 4096);  \
  }
    STG_I(0, 0); STG_I(1, 1); STG_I(2, 2);
    for (int kt = 0; kt < 64; ++kt) {
      if (kt < 62) PSYNC(8);
      else if (kt == 62) PSYNC(4);
      else PSYNC(0);
      if (kt + 3 < 64) STG_I(kt + 3, (kt + 3) & 3);
      const bf16* As = smem + (kt & 3) * 8192;
      const bf16* Bs = As + 4096;
      bf16x8 a[4], b[4];
#pragma unroll
      for (int i = 0; i < 4; ++i) a[i] = ldfrag32(As, wrg + i * 16);
#pragma unroll
      for (int i = 0; i < 4; ++i) b[i] = ldfrag32(Bs, wcg + i * 16);
#pragma unroll
      for (int mi = 0; mi < 4; ++mi)
#pragma unroll
        for (int ni = 0; ni < 4; ++ni)
          acc[mi][ni] = mfma16(a[mi], b[ni], acc[mi][ni]);
    }
#undef STG_I
#pragma unroll
    for (int mi = 0; mi < 4; ++mi)
#pragma unroll
      for (int ni = 0; ni < 4; ++ni)
#pragma unroll
        for (int ii = 0; ii < 4; ++ii) {
          int row = m0 + wrg + mi * 16 + k8 * 4 + ii;
          int col = n0 + wcg + ni * 16 + l16;
          GIw[(size_t)row * kH3 + col] = __float2bfloat16(acc[mi][ni][ii] + b_ih[col]);
        }
  }
}

// ---------- host ----------

extern "C" void kernel_launch(void* const* d_in, const int* in_sizes, int n_in,
                              void* d_out, int out_size, void* d_ws, size_t ws_size,
                              hipStream_t stream) {
  const float* prev_state  = (const float*)d_in[0];
  const float* actions     = (const float*)d_in[1];
  const float* prev_belief = (const float*)d_in[2];
  const float* eps         = (const float*)d_in[3];
  const float* W_ih        = (const float*)d_in[4];
  const float* W_hh        = (const float*)d_in[5];
  const float* b_ih        = (const float*)d_in[6];
  const float* b_hh        = (const float*)d_in[7];
  const float* W_tp        = (const float*)d_in[8];
  const float* b_tp        = (const float*)d_in[9];
  const float* W_post      = (const float*)d_in[10];
  const float* b_post      = (const float*)d_in[11];

  float* out_beliefs = (float*)d_out;                          // [T,B,H]
  float* out_states  = out_beliefs + (size_t)kT * kB * kH;     // [T,B,S]
  float* out_means   = out_states + (size_t)kT * kB * kS;
  float* out_stds    = out_means + (size_t)kT * kB * kS;

  size_t off = 0;
  auto alloc = [&](size_t bytes) {
    void* r = (char*)d_ws + off;
    off += (bytes + 255) & ~(size_t)255;
    return r;
  };
  const int nFlagWords = (kT + 2) * 4 * 32;   // 4 flags/launch, 128B apart
  unsigned* flags = (unsigned*)alloc((size_t)nFlagWords * sizeof(unsigned));
  bf16* Wih_b  = (bf16*)alloc((size_t)kH3 * kH * 2);
  bf16* Whh_b  = (bf16*)alloc((size_t)kH3 * kH * 2);
  bf16* WtpT   = (bf16*)alloc((size_t)kH * kS * 2);     // [H][S]
  bf16* WpostT = (bf16*)alloc((size_t)kS2 * kH * 2);    // [2S][H]
  bf16* actb   = (bf16*)alloc((size_t)kT * kB * kH * 2);
  bf16* hid0   = (bf16*)alloc((size_t)kB * kH * 2);
  bf16* hid1   = (bf16*)alloc((size_t)kB * kH * 2);
  bf16* hid[2] = {hid0, hid1};
  bf16* stateb = (bf16*)alloc((size_t)kB * kS * 2);
  bf16* bb0    = (bf16*)alloc((size_t)kB * kH * 2);
  bf16* bb1    = (bf16*)alloc((size_t)kB * kH * 2);
  bf16* bb[2]  = {bb0, bb1};
  float* belief_f32 = (float*)alloc((size_t)kB * kH * 4);
  bf16* GI = (bf16*)alloc((size_t)2 * kB * kH3 * 2);    // 2-step ring

  // prep
  k_zero<<<dim3((nFlagWords + 63) / 64), dim3(64), 0, stream>>>(flags, nFlagWords);
  k_cvt<<<dim3(kH3 * kH / 1024), 256, 0, stream>>>(W_ih, Wih_b, kH3 * kH);
  k_cvt<<<dim3(kH3 * kH / 1024), 256, 0, stream>>>(W_hh, Whh_b, kH3 * kH);
  k_cvt<<<dim3(kB * kS / 1024), 256, 0, stream>>>(prev_state, stateb, kB * kS);
  k_cvt_belief<<<dim3(kB * kH / 1024), 256, 0, stream>>>(prev_belief, bb0, belief_f32, kB * kH);
  k_transpose<<<dim3(kH / 32, kS / 32), 256, 0, stream>>>(W_tp, WtpT, kS, kH);
  k_transpose<<<dim3(kS2 / 32, kH / 32), 256, 0, stream>>>(W_post, WpostT, kH, kS2);
  k_actb<<<dim3(kT * kB / 64), 256, 0, stream>>>(actions, W_tp + (size_t)kS * kH, b_tp, actb);

  // one mega launch per step u: {hidden(u), post(u-1), gi(u-1), gru(u-2)}
  auto mega = [&](int u, int doH, int doP, int doGi, int doGru) {
    const int up = (u > 0) ? u - 1 : 0;     // post/gi time index
    const int ug = (u > 1) ? u - 2 : 0;     // gru time index
    k_mega<<<dim3(480), dim3(256), 0, stream>>>(
        stateb, WtpT, actb + (size_t)(doH ? u : 0) * kB * kH, hid[u & 1],
        doH, doP,
        hid[(u + 1) & 1], WpostT, b_post, eps + (size_t)up * kB * kS,
        out_means + (size_t)up * kB * kS, out_stds + (size_t)up * kB * kS,
        out_states + (size_t)up * kB * kS, doP,
        Wih_b, b_ih, GI + (size_t)((u + 1) & 1) * kB * kH3, doGi,
        Whh_b, b_hh, GI + (size_t)(u & 1) * kB * kH3, belief_f32,
        out_beliefs + (size_t)ug * kB * kH, bb[u & 1], bb[(u + 1) & 1], doGru,
        flags + (size_t)4 * 32 * u);
  };
  for (int u = 0; u < kT; ++u) mega(u, 1, u > 0, u > 0, u >= 2);
  mega(kT, 0, 1, 1, 1);          // post(63), gi(63), gru(62)
  mega(kT + 1, 0, 0, 0, 1);      // gru(63)
}